// Round 1
// baseline (65.277 us; speedup 1.0000x reference)
//
#include <hip/hip_runtime.h>
#include <cfloat>

// Problem constants (from reference setup_inputs)
constexpr int B = 4;
constexpr int N = 8192;          // points per cloud (pred and gt both 8192)
constexpr int Q = 4;             // query points per thread
constexpr int BLK = 256;         // threads per block
constexpr int QPB = Q * BLK;     // 1024 queries per block
constexpr int NQG = N / QPB;     // 8 query groups per batch
constexpr int CHUNK = 1024;      // target points staged per block
constexpr int NCH = N / CHUNK;   // 8 target chunks
constexpr int DIR_BLOCKS = B * NQG * NCH;   // 256
constexpr int MAIN_BLOCKS = 2 * DIR_BLOCKS; // 512 (both directions in one launch)

// ws layout: uint mins[2][B][N] (min1 then min2, as float bit patterns),
// then float partial[16] (8 per-batch sums, 8 per-batch maxes)
constexpr int MINS_ELEMS = 2 * B * N;       // 65536

__global__ void init_min(unsigned int* __restrict__ mins) {
    int i = blockIdx.x * blockDim.x + threadIdx.x;
    if (i < MINS_ELEMS) mins[i] = 0x7F800000u;  // +inf
}

__global__ __launch_bounds__(BLK) void chamfer_main(
        const float* __restrict__ pred, const float* __restrict__ gt,
        unsigned int* __restrict__ mins) {
    int bid = blockIdx.x;
    int dir = bid / DIR_BLOCKS;       // 0: query=pred,target=gt -> min1 ; 1: swapped -> min2
    int r   = bid % DIR_BLOCKS;
    int b   = r / (NQG * NCH);
    int r2  = r % (NQG * NCH);
    int qg  = r2 / NCH;
    int ch  = r2 % NCH;

    const float* qry = dir ? gt : pred;
    const float* tgt = dir ? pred : gt;
    unsigned int* omin = mins + dir * (B * N) + b * N;

    // Stage target chunk as (-2x, -2y, -2z, |g|^2): inner loop is then
    // t = dot3(p, g') + |g|^2 via 3 fma, and d = t + |p|^2 (folded out of loop).
    __shared__ float4 s[CHUNK];
    const float* tbase = tgt + (size_t)b * N * 3 + (size_t)ch * CHUNK * 3;
    for (int j = threadIdx.x; j < CHUNK; j += BLK) {
        float x = tbase[j * 3 + 0];
        float y = tbase[j * 3 + 1];
        float z = tbase[j * 3 + 2];
        s[j] = make_float4(-2.f * x, -2.f * y, -2.f * z,
                           fmaf(x, x, fmaf(y, y, z * z)));
    }
    __syncthreads();

    // Load Q query points per thread (stride BLK for coalescing)
    float px[Q], py[Q], pz[Q], pn[Q], mn[Q];
    const float* qbase = qry + (size_t)b * N * 3 + (size_t)qg * QPB * 3;
#pragma unroll
    for (int q = 0; q < Q; ++q) {
        int qi = threadIdx.x + q * BLK;
        px[q] = qbase[qi * 3 + 0];
        py[q] = qbase[qi * 3 + 1];
        pz[q] = qbase[qi * 3 + 2];
        pn[q] = fmaf(px[q], px[q], fmaf(py[q], py[q], pz[q] * pz[q]));
        mn[q] = FLT_MAX;
    }

    // Inner loop: 4 VALU ops per (query, target) pair; LDS read is a
    // wave-wide broadcast (conflict-free), 1 b128 per 16 VALU ops.
#pragma unroll 4
    for (int j = 0; j < CHUNK; ++j) {
        float4 g = s[j];
#pragma unroll
        for (int q = 0; q < Q; ++q) {
            float t = fmaf(px[q], g.x, fmaf(py[q], g.y, fmaf(pz[q], g.z, g.w)));
            mn[q] = fminf(mn[q], t);
        }
    }

#pragma unroll
    for (int q = 0; q < Q; ++q) {
        float d = fmaxf(mn[q] + pn[q], 0.f);   // clamp: keeps uint-bit ordering valid
        int qi = qg * QPB + threadIdx.x + q * BLK;
        atomicMin(&omin[qi], __float_as_uint(d));
    }
}

__global__ __launch_bounds__(256) void reduce_batch(
        const unsigned int* __restrict__ mins, float* __restrict__ partial) {
    int a = blockIdx.x;                 // a = dir*B + b, in [0, 2B)
    const unsigned int* base = mins + (size_t)a * N;
    float sum = 0.f, mx = -FLT_MAX;
    for (int i = threadIdx.x; i < N; i += 256) {
        float v = __uint_as_float(base[i]);
        sum += v;
        mx = fmaxf(mx, v);
    }
    __shared__ float ssum[256], smax[256];
    ssum[threadIdx.x] = sum;
    smax[threadIdx.x] = mx;
    __syncthreads();
    for (int st = 128; st > 0; st >>= 1) {
        if (threadIdx.x < st) {
            ssum[threadIdx.x] += ssum[threadIdx.x + st];
            smax[threadIdx.x] = fmaxf(smax[threadIdx.x], smax[threadIdx.x + st]);
        }
        __syncthreads();
    }
    if (threadIdx.x == 0) {
        partial[a] = ssum[0];           // per (dir,b) sum
        partial[2 * B + a] = smax[0];   // per (dir,b) max
    }
}

__global__ void final_combine(const float* __restrict__ partial,
                              float* __restrict__ out) {
    if (threadIdx.x == 0) {
        float csum = 0.f;
        for (int a = 0; a < 2 * B; ++a) csum += partial[a];
        float h1 = 0.f, h2 = 0.f;
        for (int b = 0; b < B; ++b) {
            h1 += partial[2 * B + b];          // dir 0 maxes
            h2 += partial[2 * B + B + b];      // dir 1 maxes
        }
        // chamfer = mean_b(mean_n min1 + mean_m min2) = (sum all)/(B*N)
        out[0] = csum / (float)(B * N);
        // hausdorff = mean_b(max min1) + mean_b(max min2)
        out[1] = (h1 + h2) / (float)B;
    }
}

extern "C" void kernel_launch(void* const* d_in, const int* in_sizes, int n_in,
                              void* d_out, int out_size, void* d_ws, size_t ws_size,
                              hipStream_t stream) {
    const float* pred = (const float*)d_in[0];
    const float* gt   = (const float*)d_in[1];
    float* out = (float*)d_out;

    unsigned int* mins = (unsigned int*)d_ws;
    float* partial = (float*)((char*)d_ws + (size_t)MINS_ELEMS * sizeof(unsigned int));

    init_min<<<(MINS_ELEMS + 255) / 256, 256, 0, stream>>>(mins);
    chamfer_main<<<MAIN_BLOCKS, BLK, 0, stream>>>(pred, gt, mins);
    reduce_batch<<<2 * B, 256, 0, stream>>>(mins, partial);
    final_combine<<<1, 64, 0, stream>>>(partial, out);
}